// Round 6
// baseline (73.987 us; speedup 1.0000x reference)
//
#include <hip/hip_runtime.h>
#include <math.h>

// np.float32(sqrt(2)) == 0x3FB504F3
#define SQRT2F   1.41421356237309504880f
#define EPSF     1e-32f
#define BTOL     3e-5f   // fast-path x_log abs error in decision range (|x_log|<=10)
                         // is <~6e-6 (1-ulp v_log + rcp-mul); band is 5x that.

typedef float floatx4 __attribute__((ext_vector_type(4)));  // nontemporal-store-legal

__device__ __forceinline__ float quant_one(float xe, float ze, float ce, float le,
                                           float sc, float rsc, float lo)
{
    // ---- fast f32 estimate of x_log (cheap: 1 mul, 1 v_log, 1 mul) ----
    float axe_e = fabsf(xe * rsc) + EPSF;
    bool  is_s2 = (ce == SQRT2F);
    float xlg;
    if (is_s2) {
        xlg = 2.0f * __log2f(axe_e);            // log_sqrt2(v) == 2*log2(v)
    } else {
        xlg = __logf(axe_e) / logf(ce);         // generic fallback (unused here)
    }
    float xi = rintf(xlg);
    float t  = xlg - xi;                        // in [-0.5, 0.5]
    if (fabsf(fabsf(t) - 0.5f) < BTOL) {
        // Exact idealized-f32-numpy emulation near the round-half boundary:
        // IEEE f32 div, f32 +eps, correctly-rounded f32 logs, IEEE f32 div,
        // rintf = half-even at the exact f32 tie values.
        float axe = fabsf(xe / sc) + EPSF;
        float L32 = (float)log((double)axe);
        float D32 = (float)log((double)ce);
        xi = rintf(L32 / D32);
    }

    float xc1 = fmaxf(xi - ze, lo);             // clamp(min=lo)
    float xc  = fminf(xc1 - le, -1.0f);         // clamp(max=-1)
    float e   = xc + le + ze;                   // integer in [-1,9] unless zeroed

    float q;
    if (is_s2) {
        // approx_factor * sqrt(2) == 1.5 exactly:
        //   e even: q = 2^(e/2);  e odd: q = 1.5 * 2^((e-1)/2)   (both exact)
        int ei = (int)e;
        q = (ei & 1) ? ldexpf(1.5f, (ei - 1) >> 1)
                     : ldexpf(1.0f, ei >> 1);
    } else {
        q = powf(ce, e);
    }

    q = copysignf(q, xe);                       // s=sign(x); x==0 is zero-flagged below
    if (xc1 <= lo) q = 0.0f;                    // zero_flag
    return q * sc;
}

// C=4096 rows, F=4096 cols; 8 contiguous elements (2x float4) per thread.
__global__ __launch_bounds__(256) void uaq_kernel(
    const float4* __restrict__ x,
    const float*  __restrict__ scale,     // (C,)
    const float4* __restrict__ zero,
    const float4* __restrict__ code,
    const float4* __restrict__ level,
    const float*  __restrict__ asym,      // (C,)
    floatx4* __restrict__ out,
    int n8)
{
    int i = blockIdx.x * blockDim.x + threadIdx.x;
    if (i >= n8) return;

    int row = i >> 9;                     // F/8 = 512 threads per row
    float sc  = scale[row];
    float rsc = 1.0f / sc;                // one IEEE div per 8 elements
    float lo  = fmaf(-0.5f, asym[row], -1.0f);  // exact for asym in {0,1}

    int b = i * 2;
    #pragma unroll
    for (int h = 0; h < 2; ++h) {
        float4 xv = x[b + h];
        float4 zv = zero[b + h];
        float4 cv = code[b + h];
        float4 lv = level[b + h];
        floatx4 ov;
        ov.x = quant_one(xv.x, zv.x, cv.x, lv.x, sc, rsc, lo);
        ov.y = quant_one(xv.y, zv.y, cv.y, lv.y, sc, rsc, lo);
        ov.z = quant_one(xv.z, zv.z, cv.z, lv.z, sc, rsc, lo);
        ov.w = quant_one(xv.w, zv.w, cv.w, lv.w, sc, rsc, lo);
        // nontemporal: don't let the 64 MiB output evict L3-resident inputs
        __builtin_nontemporal_store(ov, &out[b + h]);
    }
}

extern "C" void kernel_launch(void* const* d_in, const int* in_sizes, int n_in,
                              void* d_out, int out_size, void* d_ws, size_t ws_size,
                              hipStream_t stream) {
    const float* x     = (const float*)d_in[0];
    const float* scale = (const float*)d_in[1];
    const float* zero  = (const float*)d_in[2];
    const float* code  = (const float*)d_in[3];
    const float* level = (const float*)d_in[4];
    const float* asym  = (const float*)d_in[5];
    float* out = (float*)d_out;

    int n  = out_size;          // 4096*4096
    int n8 = n / 8;

    int block = 256;
    int grid  = (n8 + block - 1) / block;

    uaq_kernel<<<grid, block, 0, stream>>>(
        (const float4*)x, scale, (const float4*)zero, (const float4*)code,
        (const float4*)level, asym, (floatx4*)out, n8);
}

// Round 7
// 64.684 us; speedup vs baseline: 1.1438x; 1.1438x over previous
//
#include <hip/hip_runtime.h>
#include <math.h>

// np.float32(sqrt(2)) == 0x3FB504F3
#define SQRT2F   1.41421356237309504880f
#define EPSF     1e-32f
#define BTOL     3e-5f   // fast-path x_log abs error in decision range (|x_log|<=10)
                         // is <~6e-6 (1-ulp v_log + rcp-mul); band is 5x that.

__device__ __forceinline__ float quant_one(float xe, float ze, float ce, float le,
                                           float sc, float rsc, float lo)
{
    // ---- fast f32 estimate of x_log (1 mul, 1 v_log_f32, 1 mul) ----
    float axe_e = fabsf(xe * rsc) + EPSF;
    bool  is_s2 = (ce == SQRT2F);
    float xlg;
    if (is_s2) {
        xlg = 2.0f * __log2f(axe_e);            // log_sqrt2(v) == 2*log2(v)
    } else {
        xlg = __logf(axe_e) / logf(ce);         // generic fallback (unused here)
    }
    float xi = rintf(xlg);
    float t  = xlg - xi;                        // in [-0.5, 0.5]
    if (fabsf(fabsf(t) - 0.5f) < BTOL) {
        // Exact idealized-f32-numpy emulation near the round-half boundary:
        // IEEE f32 div, f32 +eps, correctly-rounded f32 logs, IEEE f32 div,
        // rintf = half-even at the exact f32 tie values.
        float axe = fabsf(xe / sc) + EPSF;
        float L32 = (float)log((double)axe);
        float D32 = (float)log((double)ce);
        xi = rintf(L32 / D32);
    }

    float xc1 = fmaxf(xi - ze, lo);             // clamp(min=lo)
    float xc  = fminf(xc1 - le, -1.0f);         // clamp(max=-1)
    float e   = xc + le + ze;                   // integer in [-1,9] unless zeroed

    float q;
    if (is_s2) {
        // approx_factor * sqrt(2) == 1.5 exactly:
        //   e even: q = 2^(e/2);  e odd: q = 1.5 * 2^((e-1)/2)   (both exact)
        int ei = (int)e;
        q = (ei & 1) ? ldexpf(1.5f, (ei - 1) >> 1)
                     : ldexpf(1.0f, ei >> 1);
    } else {
        q = powf(ce, e);
    }

    q = copysignf(q, xe);                       // s=sign(x); x==0 is zero-flagged below
    if (xc1 <= lo) q = 0.0f;                    // zero_flag
    return q * sc;
}

// C=4096 rows, F=4096 cols; 4 contiguous elements (1 float4) per thread,
// lane-contiguous 16B/lane — the proven round-4 memory structure.
__global__ __launch_bounds__(256) void uaq_kernel(
    const float4* __restrict__ x,
    const float*  __restrict__ scale,     // (C,)
    const float4* __restrict__ zero,
    const float4* __restrict__ code,
    const float4* __restrict__ level,
    const float*  __restrict__ asym,      // (C,)
    float4* __restrict__ out,
    int n4)
{
    int i = blockIdx.x * blockDim.x + threadIdx.x;
    if (i >= n4) return;

    int row = i >> 10;                    // F/4 = 1024 threads per row
    float sc  = scale[row];
    float rsc = 1.0f / sc;                // one IEEE div per 4 elements
    float lo  = fmaf(-0.5f, asym[row], -1.0f);  // exact for asym in {0,1}

    float4 xv = x[i];
    float4 zv = zero[i];
    float4 cv = code[i];
    float4 lv = level[i];
    float4 ov;
    ov.x = quant_one(xv.x, zv.x, cv.x, lv.x, sc, rsc, lo);
    ov.y = quant_one(xv.y, zv.y, cv.y, lv.y, sc, rsc, lo);
    ov.z = quant_one(xv.z, zv.z, cv.z, lv.z, sc, rsc, lo);
    ov.w = quant_one(xv.w, zv.w, cv.w, lv.w, sc, rsc, lo);
    out[i] = ov;
}

extern "C" void kernel_launch(void* const* d_in, const int* in_sizes, int n_in,
                              void* d_out, int out_size, void* d_ws, size_t ws_size,
                              hipStream_t stream) {
    const float* x     = (const float*)d_in[0];
    const float* scale = (const float*)d_in[1];
    const float* zero  = (const float*)d_in[2];
    const float* code  = (const float*)d_in[3];
    const float* level = (const float*)d_in[4];
    const float* asym  = (const float*)d_in[5];
    float* out = (float*)d_out;

    int n  = out_size;          // 4096*4096
    int n4 = n / 4;

    int block = 256;
    int grid  = (n4 + block - 1) / block;

    uaq_kernel<<<grid, block, 0, stream>>>(
        (const float4*)x, scale, (const float4*)zero, (const float4*)code,
        (const float4*)level, asym, (float4*)out, n4);
}